// Round 1
// baseline (1056.843 us; speedup 1.0000x reference)
//
#include <hip/hip_runtime.h>
#include <hip/hip_bf16.h>

#define N_NODES 50000
#define N_EDGES 400000
#define E_TOT   450000   // + self loops
#define N_GRAPHS 256
#define F_IN 128
#define HID 64

static __device__ __forceinline__ unsigned enc_f(float f) {
    unsigned u = __float_as_uint(f);
    return (u & 0x80000000u) ? ~u : (u | 0x80000000u);
}
static __device__ __forceinline__ float dec_f(unsigned u) {
    return (u & 0x80000000u) ? __uint_as_float(u & 0x7FFFFFFFu) : __uint_as_float(~u);
}

// ---------------- degree / norm ----------------
__global__ void k_deg(const int* __restrict__ dstp, int* __restrict__ degi) {
    int e = blockIdx.x * blockDim.x + threadIdx.x;
    if (e < N_EDGES) atomicAdd(&degi[dstp[e]], 1);
}

__global__ void k_dinv(const int* __restrict__ degi, float* __restrict__ dinv) {
    int i = blockIdx.x * blockDim.x + threadIdx.x;
    if (i < N_NODES) dinv[i] = rsqrtf(1.0f + (float)degi[i]);  // self-loop => deg>=1
}

__global__ void k_norm(const int* __restrict__ srcp, const int* __restrict__ dstp,
                       const float* __restrict__ dinv, float* __restrict__ norm) {
    int e = blockIdx.x * blockDim.x + threadIdx.x;
    if (e >= E_TOT) return;
    int s, d;
    if (e < N_EDGES) { s = srcp[e]; d = dstp[e]; } else { s = d = e - N_EDGES; }
    norm[e] = dinv[s] * dinv[d];
}

// ---------------- GEMM: out[r, col_off + j] = sum_k x[r,k] * w[k, col_off + j] ----------------
// block = 256 threads, handles 64 rows x 64 cols; w tile staged in LDS.
template <int K>
__global__ void k_gemm64(const float* __restrict__ x, const float* __restrict__ w,
                         float* __restrict__ out, int ncol, int nrows) {
    __shared__ float sw[K * 64];
    int col_off = blockIdx.y * 64;
    for (int i = threadIdx.x; i < K * 64; i += 256) {
        int k = i >> 6, j = i & 63;
        sw[i] = w[k * ncol + col_off + j];
    }
    __syncthreads();
    int row0 = blockIdx.x * 64;
#pragma unroll
    for (int it = 0; it < 16; ++it) {
        int idx = it * 256 + threadIdx.x;
        int r = row0 + (idx >> 6);
        int j = idx & 63;
        if (r < nrows) {
            const float* xr = x + (size_t)r * K;
            float acc = 0.f;
#pragma unroll
            for (int k = 0; k < K; ++k) acc = fmaf(xr[k], sw[k * 64 + j], acc);
            out[(size_t)r * ncol + col_off + j] = acc;
        }
    }
}

// ---------------- GCN aggregate ----------------
__global__ void k_init_bias(float* __restrict__ out, const float* __restrict__ b) {
    int i = blockIdx.x * blockDim.x + threadIdx.x;
    if (i < N_NODES * HID) out[i] = b[i & 63];
}

__global__ void k_gcn_agg(const int* __restrict__ srcp, const int* __restrict__ dstp,
                          const float* __restrict__ norm, const float* __restrict__ t,
                          float* __restrict__ out) {
    int gid = blockIdx.x * blockDim.x + threadIdx.x;
    if (gid >= E_TOT * HID) return;
    int e = gid >> 6, f = gid & 63;
    int s, d;
    if (e < N_EDGES) { s = srcp[e]; d = dstp[e]; } else { s = d = e - N_EDGES; }
    atomicAdd(&out[d * 64 + f], t[s * 64 + f] * norm[e]);
}

__global__ void k_relu(float* __restrict__ a, int n) {
    int i = blockIdx.x * blockDim.x + threadIdx.x;
    if (i < n) a[i] = fmaxf(a[i], 0.f);
}

// ---------------- GAT ----------------
__global__ void k_att(const float* __restrict__ hg, const float* __restrict__ att_src,
                      const float* __restrict__ att_dst,
                      float* __restrict__ asrc, float* __restrict__ adst) {
    int i = blockIdx.x * blockDim.x + threadIdx.x;  // n*4 + h
    if (i >= N_NODES * 4) return;
    int n = i >> 2, h = i & 3;
    const float* hp = hg + (size_t)n * 256 + h * 64;
    float s1 = 0.f, s2 = 0.f;
#pragma unroll
    for (int c = 0; c < 64; ++c) {
        float v = hp[c];
        s1 = fmaf(v, att_src[h * 64 + c], s1);
        s2 = fmaf(v, att_dst[h * 64 + c], s2);
    }
    asrc[i] = s1;
    adst[i] = s2;
}

__global__ void k_edge_e(const int* __restrict__ srcp, const int* __restrict__ dstp,
                         const float* __restrict__ asrc, const float* __restrict__ adst,
                         float* __restrict__ ebuf, unsigned* __restrict__ menc) {
    int i = blockIdx.x * blockDim.x + threadIdx.x;  // e*4 + h
    if (i >= E_TOT * 4) return;
    int e = i >> 2, h = i & 3;
    int s, d;
    if (e < N_EDGES) { s = srcp[e]; d = dstp[e]; } else { s = d = e - N_EDGES; }
    float v = asrc[s * 4 + h] + adst[d * 4 + h];
    v = v >= 0.f ? v : 0.2f * v;  // leaky_relu 0.2
    ebuf[i] = v;
    atomicMax(&menc[d * 4 + h], enc_f(v));
}

__global__ void k_edge_exp(const int* __restrict__ dstp, const unsigned* __restrict__ menc,
                           float* __restrict__ ebuf, float* __restrict__ denom) {
    int i = blockIdx.x * blockDim.x + threadIdx.x;
    if (i >= E_TOT * 4) return;
    int e = i >> 2, h = i & 3;
    int d = (e < N_EDGES) ? dstp[e] : e - N_EDGES;
    float ex = expf(ebuf[i] - dec_f(menc[d * 4 + h]));
    ebuf[i] = ex;
    atomicAdd(&denom[d * 4 + h], ex);
}

__global__ void k_alpha(const int* __restrict__ dstp, const float* __restrict__ denom,
                        float* __restrict__ ebuf) {
    int i = blockIdx.x * blockDim.x + threadIdx.x;
    if (i >= E_TOT * 4) return;
    int e = i >> 2, h = i & 3;
    int d = (e < N_EDGES) ? dstp[e] : e - N_EDGES;
    ebuf[i] = ebuf[i] / denom[d * 4 + h];
}

__global__ void k_gat_agg(const int* __restrict__ srcp, const int* __restrict__ dstp,
                          const float* __restrict__ ebuf, const float* __restrict__ hg,
                          float* __restrict__ gout) {
    int gid = blockIdx.x * blockDim.x + threadIdx.x;
    if (gid >= E_TOT * 64) return;
    int e = gid >> 6, c = gid & 63;
    int s, d;
    if (e < N_EDGES) { s = srcp[e]; d = dstp[e]; } else { s = d = e - N_EDGES; }
    const float* hp = hg + (size_t)s * 256 + c;
    float a0 = ebuf[e * 4 + 0], a1 = ebuf[e * 4 + 1];
    float a2 = ebuf[e * 4 + 2], a3 = ebuf[e * 4 + 3];
    float v = a0 * hp[0] + a1 * hp[64] + a2 * hp[128] + a3 * hp[192];
    atomicAdd(&gout[d * 64 + c], v);
}

__global__ void k_headmean(const float* __restrict__ gout, const float* __restrict__ gb,
                           float* __restrict__ out) {
    int i = blockIdx.x * blockDim.x + threadIdx.x;
    if (i >= N_NODES * HID) return;
    float v = gout[i] * 0.25f + gb[i & 63];
    out[i] = fmaxf(v, 0.f);
}

// ---------------- pool + classifier ----------------
__global__ void k_pool(const int* __restrict__ batch, const float* __restrict__ h,
                       float* __restrict__ psum, float* __restrict__ pcnt) {
    int i = blockIdx.x * blockDim.x + threadIdx.x;
    if (i >= N_NODES * HID) return;
    int n = i >> 6, c = i & 63;
    int g = batch[n];
    atomicAdd(&psum[g * 64 + c], h[i]);
    if (c == 0) atomicAdd(&pcnt[g], 1.0f);
}

__global__ void k_cls(const float* __restrict__ psum, const float* __restrict__ pcnt,
                      const float* __restrict__ cw1, const float* __restrict__ cb1,
                      const float* __restrict__ cw2, const float* __restrict__ cb2,
                      float* __restrict__ out) {
    int g = blockIdx.x;
    int j = threadIdx.x;  // 64 threads; j<32 compute z
    __shared__ float sp[64];
    float rc = 1.0f / fmaxf(pcnt[g], 1.0f);
    sp[j] = psum[g * 64 + j] * rc;
    __syncthreads();
    float z = 0.f;
    if (j < 32) {
        float acc = 0.f;
#pragma unroll
        for (int k = 0; k < 64; ++k) acc = fmaf(sp[k], cw1[k * 32 + j], acc);
        acc += cb1[j];
        acc = fmaxf(acc, 0.f);
        z = acc * cw2[j];
    }
#pragma unroll
    for (int off = 32; off; off >>= 1) z += __shfl_down(z, off);
    if (j == 0) out[g] = z + cb2[0];
}

extern "C" void kernel_launch(void* const* d_in, const int* in_sizes, int n_in,
                              void* d_out, int out_size, void* d_ws, size_t ws_size,
                              hipStream_t stream) {
    const float* x       = (const float*)d_in[0];
    const int*   ei      = (const int*)d_in[1];
    const int*   batch   = (const int*)d_in[2];
    const float* w1      = (const float*)d_in[3];
    const float* b1      = (const float*)d_in[4];
    const float* w2      = (const float*)d_in[5];
    const float* b2      = (const float*)d_in[6];
    const float* w3      = (const float*)d_in[7];
    const float* b3      = (const float*)d_in[8];
    const float* gat_w   = (const float*)d_in[9];
    const float* att_src = (const float*)d_in[10];
    const float* att_dst = (const float*)d_in[11];
    const float* gat_b   = (const float*)d_in[12];
    const float* cw1     = (const float*)d_in[13];
    const float* cb1     = (const float*)d_in[14];
    const float* cw2     = (const float*)d_in[15];
    const float* cb2     = (const float*)d_in[16];
    float* out = (float*)d_out;

    const int* srcp = ei;
    const int* dstp = ei + N_EDGES;

    // workspace layout (floats)
    float* W = (float*)d_ws;
    size_t off = 0;
    float*    dinv  = W + off; off += N_NODES;            // 50000
    int*      degi  = (int*)(W + off); off += N_NODES;    // 50000
    float*    norm  = W + off; off += E_TOT;              // 450000
    float*    bufT  = W + off; off += (size_t)N_NODES * HID;
    float*    bufA  = W + off; off += (size_t)N_NODES * HID;
    float*    bufB  = W + off; off += (size_t)N_NODES * HID;
    float*    hg    = W + off; off += (size_t)N_NODES * 256;
    float*    asrc  = W + off; off += (size_t)N_NODES * 4;
    float*    adst  = W + off; off += (size_t)N_NODES * 4;
    unsigned* menc  = (unsigned*)(W + off); off += (size_t)N_NODES * 4;
    float*    denom = W + off; off += (size_t)N_NODES * 4;
    float*    ebuf  = W + off; off += (size_t)E_TOT * 4;
    float*    gout  = W + off; off += (size_t)N_NODES * HID;
    float*    psum  = W + off; off += (size_t)N_GRAPHS * HID;
    float*    pcnt  = W + off; off += N_GRAPHS;

    auto cdiv = [](int a, int b) { return (a + b - 1) / b; };

    // zero accumulators
    hipMemsetAsync(degi, 0, N_NODES * sizeof(int), stream);
    hipMemsetAsync(menc, 0, N_NODES * 4 * sizeof(unsigned), stream);
    hipMemsetAsync(denom, 0, N_NODES * 4 * sizeof(float), stream);
    hipMemsetAsync(gout, 0, (size_t)N_NODES * HID * sizeof(float), stream);
    hipMemsetAsync(psum, 0, (N_GRAPHS * HID + N_GRAPHS) * sizeof(float), stream);  // psum + pcnt

    // degree / norm
    k_deg<<<cdiv(N_EDGES, 256), 256, 0, stream>>>(dstp, degi);
    k_dinv<<<cdiv(N_NODES, 256), 256, 0, stream>>>(degi, dinv);
    k_norm<<<cdiv(E_TOT, 256), 256, 0, stream>>>(srcp, dstp, dinv, norm);

    const int nEW = cdiv(N_NODES * HID, 256);      // elementwise over node features
    const int nAG = cdiv(E_TOT * HID, 256);        // edge x feature
    const int nEH = cdiv(E_TOT * 4, 256);          // edge x head
    dim3 g64(cdiv(N_NODES, 64), 1);

    // GCN layer 1 (K=128): x -> bufA
    k_gemm64<F_IN><<<g64, 256, 0, stream>>>(x, w1, bufT, HID, N_NODES);
    k_init_bias<<<nEW, 256, 0, stream>>>(bufA, b1);
    k_gcn_agg<<<nAG, 256, 0, stream>>>(srcp, dstp, norm, bufT, bufA);
    k_relu<<<nEW, 256, 0, stream>>>(bufA, N_NODES * HID);

    // GCN layer 2: bufA -> bufB
    k_gemm64<HID><<<g64, 256, 0, stream>>>(bufA, w2, bufT, HID, N_NODES);
    k_init_bias<<<nEW, 256, 0, stream>>>(bufB, b2);
    k_gcn_agg<<<nAG, 256, 0, stream>>>(srcp, dstp, norm, bufT, bufB);
    k_relu<<<nEW, 256, 0, stream>>>(bufB, N_NODES * HID);

    // GCN layer 3: bufB -> bufA
    k_gemm64<HID><<<g64, 256, 0, stream>>>(bufB, w3, bufT, HID, N_NODES);
    k_init_bias<<<nEW, 256, 0, stream>>>(bufA, b3);
    k_gcn_agg<<<nAG, 256, 0, stream>>>(srcp, dstp, norm, bufT, bufA);
    k_relu<<<nEW, 256, 0, stream>>>(bufA, N_NODES * HID);

    // GAT: hg = bufA @ gat_w  [N,256]
    dim3 gGAT(cdiv(N_NODES, 64), 4);
    k_gemm64<HID><<<gGAT, 256, 0, stream>>>(bufA, gat_w, hg, 4 * HID, N_NODES);
    k_att<<<cdiv(N_NODES * 4, 256), 256, 0, stream>>>(hg, att_src, att_dst, asrc, adst);
    k_edge_e<<<nEH, 256, 0, stream>>>(srcp, dstp, asrc, adst, ebuf, menc);
    k_edge_exp<<<nEH, 256, 0, stream>>>(dstp, menc, ebuf, denom);
    k_alpha<<<nEH, 256, 0, stream>>>(dstp, denom, ebuf);
    k_gat_agg<<<nAG, 256, 0, stream>>>(srcp, dstp, ebuf, hg, gout);
    k_headmean<<<nEW, 256, 0, stream>>>(gout, gat_b, bufB);

    // pool + classifier
    k_pool<<<nEW, 256, 0, stream>>>(batch, bufB, psum, pcnt);
    k_cls<<<N_GRAPHS, 64, 0, stream>>>(psum, pcnt, cw1, cb1, cw2, cb2, out);
}

// Round 2
// 723.053 us; speedup vs baseline: 1.4616x; 1.4616x over previous
//
#include <hip/hip_runtime.h>
#include <hip/hip_bf16.h>

#define N_NODES 50000
#define N_EDGES 400000
#define E_TOT   450000   // + self loops
#define N_GRAPHS 256
#define F_IN 128
#define HID 64
#define SCAN_NB 196      // ceil(50000/256)

// ---------------- degree / dinv ----------------
__global__ void k_deg(const int* __restrict__ dstp, int* __restrict__ degi) {
    int e = blockIdx.x * blockDim.x + threadIdx.x;
    if (e < N_EDGES) atomicAdd(&degi[dstp[e]], 1);
}

__global__ void k_dinv(const int* __restrict__ degi, float* __restrict__ dinv) {
    int i = blockIdx.x * blockDim.x + threadIdx.x;
    if (i < N_NODES) dinv[i] = rsqrtf(1.0f + (float)degi[i]);  // self-loop => deg>=1
}

// ---------------- CSR build: exclusive scan of (deg+1) ----------------
__global__ void k_scan1(const int* __restrict__ degi, int* __restrict__ rowptr,
                        int* __restrict__ partial) {
    __shared__ int s[256];
    int i = blockIdx.x * 256 + threadIdx.x;
    int v = (i < N_NODES) ? (degi[i] + 1) : 0;
    s[threadIdx.x] = v;
    __syncthreads();
    for (int off = 1; off < 256; off <<= 1) {
        int t = (threadIdx.x >= off) ? s[threadIdx.x - off] : 0;
        __syncthreads();
        s[threadIdx.x] += t;
        __syncthreads();
    }
    if (i < N_NODES) rowptr[i] = s[threadIdx.x] - v;  // exclusive within block
    if (threadIdx.x == 255) partial[blockIdx.x] = s[255];
}

__global__ void k_scan2(int* __restrict__ partial) {
    __shared__ int s[256];
    int v = (threadIdx.x < SCAN_NB) ? partial[threadIdx.x] : 0;
    s[threadIdx.x] = v;
    __syncthreads();
    for (int off = 1; off < 256; off <<= 1) {
        int t = (threadIdx.x >= off) ? s[threadIdx.x - off] : 0;
        __syncthreads();
        s[threadIdx.x] += t;
        __syncthreads();
    }
    if (threadIdx.x < SCAN_NB) partial[threadIdx.x] = s[threadIdx.x] - v;  // exclusive
}

__global__ void k_scan3(int* __restrict__ rowptr, const int* __restrict__ partial) {
    int i = blockIdx.x * 256 + threadIdx.x;
    if (i < N_NODES) rowptr[i] += partial[blockIdx.x];
    if (i == 0) rowptr[N_NODES] = E_TOT;
}

// self edge goes in slot 0 of each node's bucket; cursor starts at 1
__global__ void k_fill_self(const int* __restrict__ rowptr, const float* __restrict__ dinv,
                            int* __restrict__ csr_src, float* __restrict__ csr_norm,
                            int* __restrict__ cursor) {
    int i = blockIdx.x * blockDim.x + threadIdx.x;
    if (i >= N_NODES) return;
    int p = rowptr[i];
    csr_src[p] = i;
    float di = dinv[i];
    csr_norm[p] = di * di;
    cursor[i] = 1;
}

__global__ void k_fill_edge(const int* __restrict__ srcp, const int* __restrict__ dstp,
                            const int* __restrict__ rowptr, const float* __restrict__ dinv,
                            int* __restrict__ cursor, int* __restrict__ csr_src,
                            float* __restrict__ csr_norm) {
    int e = blockIdx.x * blockDim.x + threadIdx.x;
    if (e >= N_EDGES) return;
    int s = srcp[e], d = dstp[e];
    int p = rowptr[d] + atomicAdd(&cursor[d], 1);
    csr_src[p] = s;
    csr_norm[p] = dinv[s] * dinv[d];
}

// ---------------- GEMM: out[r, col_off + j] = sum_k x[r,k] * w[k, col_off + j] ----------------
template <int K>
__global__ void k_gemm64(const float* __restrict__ x, const float* __restrict__ w,
                         float* __restrict__ out, int ncol, int nrows) {
    __shared__ float sw[K * 64];
    int col_off = blockIdx.y * 64;
    for (int i = threadIdx.x; i < K * 64; i += 256) {
        int k = i >> 6, j = i & 63;
        sw[i] = w[k * ncol + col_off + j];
    }
    __syncthreads();
    int row0 = blockIdx.x * 64;
#pragma unroll
    for (int it = 0; it < 16; ++it) {
        int idx = it * 256 + threadIdx.x;
        int r = row0 + (idx >> 6);
        int j = idx & 63;
        if (r < nrows) {
            const float* xr = x + (size_t)r * K;
            float acc = 0.f;
#pragma unroll
            for (int k = 0; k < K; ++k) acc = fmaf(xr[k], sw[k * 64 + j], acc);
            out[(size_t)r * ncol + col_off + j] = acc;
        }
    }
}

// ---------------- GCN aggregate: wave per node, gather over CSR, fused bias+ReLU ----------------
__global__ void k_gcn_gather(const int* __restrict__ rowptr, const int* __restrict__ csr_src,
                             const float* __restrict__ csr_norm, const float* __restrict__ t,
                             const float* __restrict__ b, float* __restrict__ out) {
    int node = (blockIdx.x * blockDim.x + threadIdx.x) >> 6;
    int lane = threadIdx.x & 63;
    if (node >= N_NODES) return;
    int beg = rowptr[node], end = rowptr[node + 1];
    float acc = b[lane];
    for (int p = beg; p < end; ++p) {
        int s = csr_src[p];
        float nm = csr_norm[p];
        acc = fmaf(t[(size_t)s * 64 + lane], nm, acc);
    }
    out[(size_t)node * 64 + lane] = fmaxf(acc, 0.f);
}

// ---------------- GAT ----------------
// asrc/adst: wave per node, 4 heads, wave-reduce dot products
__global__ void k_att(const float* __restrict__ hg, const float* __restrict__ att_src,
                      const float* __restrict__ att_dst,
                      float* __restrict__ asrc, float* __restrict__ adst) {
    int node = (blockIdx.x * blockDim.x + threadIdx.x) >> 6;
    int lane = threadIdx.x & 63;
    if (node >= N_NODES) return;
#pragma unroll
    for (int h = 0; h < 4; ++h) {
        float v = hg[(size_t)node * 256 + h * 64 + lane];
        float p1 = v * att_src[h * 64 + lane];
        float p2 = v * att_dst[h * 64 + lane];
#pragma unroll
        for (int off = 32; off; off >>= 1) {
            p1 += __shfl_xor(p1, off);
            p2 += __shfl_xor(p2, off);
        }
        if (lane == 0) {
            asrc[node * 4 + h] = p1;
            adst[node * 4 + h] = p2;
        }
    }
}

static __device__ __forceinline__ float lrelu02(float v) {
    return v >= 0.f ? v : 0.2f * v;
}

// fused per-node softmax + weighted aggregation + head-mean + bias + ReLU
__global__ void k_gat_fused(const int* __restrict__ rowptr, const int* __restrict__ csr_src,
                            const float* __restrict__ hg, const float* __restrict__ asrc,
                            const float* __restrict__ adst, const float* __restrict__ gb,
                            float* __restrict__ out) {
    int node = (blockIdx.x * blockDim.x + threadIdx.x) >> 6;
    int lane = threadIdx.x & 63;
    if (node >= N_NODES) return;
    int beg = rowptr[node], end = rowptr[node + 1];
    const float4* __restrict__ asrc4 = (const float4*)asrc;
    float4 ad = ((const float4*)adst)[node];
    float m0 = -1e30f, m1 = -1e30f, m2 = -1e30f, m3 = -1e30f;
    for (int p = beg; p < end; ++p) {
        int s = csr_src[p];
        float4 as = asrc4[s];
        m0 = fmaxf(m0, lrelu02(as.x + ad.x));
        m1 = fmaxf(m1, lrelu02(as.y + ad.y));
        m2 = fmaxf(m2, lrelu02(as.z + ad.z));
        m3 = fmaxf(m3, lrelu02(as.w + ad.w));
    }
    float den0 = 0.f, den1 = 0.f, den2 = 0.f, den3 = 0.f;
    float acc0 = 0.f, acc1 = 0.f, acc2 = 0.f, acc3 = 0.f;
    for (int p = beg; p < end; ++p) {
        int s = csr_src[p];
        float4 as = asrc4[s];
        float x0 = expf(lrelu02(as.x + ad.x) - m0);
        float x1 = expf(lrelu02(as.y + ad.y) - m1);
        float x2 = expf(lrelu02(as.z + ad.z) - m2);
        float x3 = expf(lrelu02(as.w + ad.w) - m3);
        den0 += x0; den1 += x1; den2 += x2; den3 += x3;
        const float* hp = hg + (size_t)s * 256 + lane;
        acc0 = fmaf(x0, hp[0],   acc0);
        acc1 = fmaf(x1, hp[64],  acc1);
        acc2 = fmaf(x2, hp[128], acc2);
        acc3 = fmaf(x3, hp[192], acc3);
    }
    float v = 0.25f * (acc0 / den0 + acc1 / den1 + acc2 / den2 + acc3 / den3) + gb[lane];
    out[(size_t)node * 64 + lane] = fmaxf(v, 0.f);
}

// ---------------- pool (batch is sorted: run-length accumulate per wave) ----------------
__global__ void k_pool2(const int* __restrict__ batch, const float* __restrict__ h,
                        float* __restrict__ psum, float* __restrict__ pcnt) {
    int wave = (blockIdx.x * blockDim.x + threadIdx.x) >> 6;
    int lane = threadIdx.x & 63;
    int n0 = wave * 64;
    if (n0 >= N_NODES) return;
    int nend = min(n0 + 64, N_NODES);
    int cur = batch[n0];
    float acc = 0.f, cnt = 0.f;
    for (int n = n0; n < nend; ++n) {
        int g = batch[n];
        if (g != cur) {
            atomicAdd(&psum[cur * 64 + lane], acc);
            if (lane == 0) atomicAdd(&pcnt[cur], cnt);
            acc = 0.f; cnt = 0.f; cur = g;
        }
        acc += h[(size_t)n * 64 + lane];
        cnt += 1.f;
    }
    atomicAdd(&psum[cur * 64 + lane], acc);
    if (lane == 0) atomicAdd(&pcnt[cur], cnt);
}

__global__ void k_cls(const float* __restrict__ psum, const float* __restrict__ pcnt,
                      const float* __restrict__ cw1, const float* __restrict__ cb1,
                      const float* __restrict__ cw2, const float* __restrict__ cb2,
                      float* __restrict__ out) {
    int g = blockIdx.x;
    int j = threadIdx.x;  // 64 threads; j<32 compute z
    __shared__ float sp[64];
    float rc = 1.0f / fmaxf(pcnt[g], 1.0f);
    sp[j] = psum[g * 64 + j] * rc;
    __syncthreads();
    float z = 0.f;
    if (j < 32) {
        float acc = 0.f;
#pragma unroll
        for (int k = 0; k < 64; ++k) acc = fmaf(sp[k], cw1[k * 32 + j], acc);
        acc += cb1[j];
        acc = fmaxf(acc, 0.f);
        z = acc * cw2[j];
    }
#pragma unroll
    for (int off = 32; off; off >>= 1) z += __shfl_down(z, off);
    if (j == 0) out[g] = z + cb2[0];
}

extern "C" void kernel_launch(void* const* d_in, const int* in_sizes, int n_in,
                              void* d_out, int out_size, void* d_ws, size_t ws_size,
                              hipStream_t stream) {
    const float* x       = (const float*)d_in[0];
    const int*   ei      = (const int*)d_in[1];
    const int*   batch   = (const int*)d_in[2];
    const float* w1      = (const float*)d_in[3];
    const float* b1      = (const float*)d_in[4];
    const float* w2      = (const float*)d_in[5];
    const float* b2      = (const float*)d_in[6];
    const float* w3      = (const float*)d_in[7];
    const float* b3      = (const float*)d_in[8];
    const float* gat_w   = (const float*)d_in[9];
    const float* att_src = (const float*)d_in[10];
    const float* att_dst = (const float*)d_in[11];
    const float* gat_b   = (const float*)d_in[12];
    const float* cw1     = (const float*)d_in[13];
    const float* cb1     = (const float*)d_in[14];
    const float* cw2     = (const float*)d_in[15];
    const float* cb2     = (const float*)d_in[16];
    float* out = (float*)d_out;

    const int* srcp = ei;
    const int* dstp = ei + N_EDGES;

    // workspace layout (floats)
    float* W = (float*)d_ws;
    size_t off = 0;
    float*    dinv    = W + off; off += N_NODES;
    int*      degi    = (int*)(W + off); off += N_NODES;
    int*      rowptr  = (int*)(W + off); off += N_NODES + 1;
    int*      partial = (int*)(W + off); off += 256;
    int*      cursor  = (int*)(W + off); off += N_NODES;
    int*      csr_src = (int*)(W + off); off += E_TOT;
    float*    csr_nrm = W + off; off += E_TOT;
    float*    bufT    = W + off; off += (size_t)N_NODES * HID;
    float*    bufA    = W + off; off += (size_t)N_NODES * HID;
    float*    bufB    = W + off; off += (size_t)N_NODES * HID;
    float*    hg      = W + off; off += (size_t)N_NODES * 256;
    float*    asrc    = W + off; off += (size_t)N_NODES * 4;
    float*    adst    = W + off; off += (size_t)N_NODES * 4;
    float*    psum    = W + off; off += (size_t)N_GRAPHS * HID;
    float*    pcnt    = W + off; off += N_GRAPHS;

    auto cdiv = [](int a, int b) { return (a + b - 1) / b; };

    hipMemsetAsync(degi, 0, N_NODES * sizeof(int), stream);
    hipMemsetAsync(psum, 0, (N_GRAPHS * HID + N_GRAPHS) * sizeof(float), stream);

    // degree / dinv / CSR
    k_deg<<<cdiv(N_EDGES, 256), 256, 0, stream>>>(dstp, degi);
    k_dinv<<<cdiv(N_NODES, 256), 256, 0, stream>>>(degi, dinv);
    k_scan1<<<SCAN_NB, 256, 0, stream>>>(degi, rowptr, partial);
    k_scan2<<<1, 256, 0, stream>>>(partial);
    k_scan3<<<SCAN_NB, 256, 0, stream>>>(rowptr, partial);
    k_fill_self<<<cdiv(N_NODES, 256), 256, 0, stream>>>(rowptr, dinv, csr_src, csr_nrm, cursor);
    k_fill_edge<<<cdiv(N_EDGES, 256), 256, 0, stream>>>(srcp, dstp, rowptr, dinv, cursor,
                                                        csr_src, csr_nrm);

    const int nWV = cdiv(N_NODES * 64, 256);  // wave-per-node kernels
    dim3 g64(cdiv(N_NODES, 64), 1);

    // GCN layer 1 (K=128): x -> bufA
    k_gemm64<F_IN><<<g64, 256, 0, stream>>>(x, w1, bufT, HID, N_NODES);
    k_gcn_gather<<<nWV, 256, 0, stream>>>(rowptr, csr_src, csr_nrm, bufT, b1, bufA);

    // GCN layer 2: bufA -> bufB
    k_gemm64<HID><<<g64, 256, 0, stream>>>(bufA, w2, bufT, HID, N_NODES);
    k_gcn_gather<<<nWV, 256, 0, stream>>>(rowptr, csr_src, csr_nrm, bufT, b2, bufB);

    // GCN layer 3: bufB -> bufA
    k_gemm64<HID><<<g64, 256, 0, stream>>>(bufB, w3, bufT, HID, N_NODES);
    k_gcn_gather<<<nWV, 256, 0, stream>>>(rowptr, csr_src, csr_nrm, bufT, b3, bufA);

    // GAT
    dim3 gGAT(cdiv(N_NODES, 64), 4);
    k_gemm64<HID><<<gGAT, 256, 0, stream>>>(bufA, gat_w, hg, 4 * HID, N_NODES);
    k_att<<<nWV, 256, 0, stream>>>(hg, att_src, att_dst, asrc, adst);
    k_gat_fused<<<nWV, 256, 0, stream>>>(rowptr, csr_src, hg, asrc, adst, gat_b, bufB);

    // pool + classifier
    k_pool2<<<cdiv(cdiv(N_NODES, 64) * 64, 256), 256, 0, stream>>>(batch, bufB, psum, pcnt);
    k_cls<<<N_GRAPHS, 64, 0, stream>>>(psum, pcnt, cw1, cb1, cw2, cb2, out);
}

// Round 3
// 624.099 us; speedup vs baseline: 1.6934x; 1.1586x over previous
//
#include <hip/hip_runtime.h>
#include <hip/hip_bf16.h>

#define N_NODES 50000
#define N_EDGES 400000
#define E_TOT   450000   // + self loops
#define N_GRAPHS 256
#define F_IN 128
#define HID 64
#define SCAN_NB 196      // ceil(50000/256)

// ---------------- degree / dinv ----------------
__global__ void k_deg(const int* __restrict__ dstp, int* __restrict__ degi) {
    int e = blockIdx.x * blockDim.x + threadIdx.x;
    if (e < N_EDGES) atomicAdd(&degi[dstp[e]], 1);
}

__global__ void k_dinv(const int* __restrict__ degi, float* __restrict__ dinv) {
    int i = blockIdx.x * blockDim.x + threadIdx.x;
    if (i < N_NODES) dinv[i] = rsqrtf(1.0f + (float)degi[i]);  // self-loop => deg>=1
}

// ---------------- CSR build: exclusive scan of (deg+1) ----------------
__global__ void k_scan1(const int* __restrict__ degi, int* __restrict__ rowptr,
                        int* __restrict__ partial) {
    __shared__ int s[256];
    int i = blockIdx.x * 256 + threadIdx.x;
    int v = (i < N_NODES) ? (degi[i] + 1) : 0;
    s[threadIdx.x] = v;
    __syncthreads();
    for (int off = 1; off < 256; off <<= 1) {
        int t = (threadIdx.x >= off) ? s[threadIdx.x - off] : 0;
        __syncthreads();
        s[threadIdx.x] += t;
        __syncthreads();
    }
    if (i < N_NODES) rowptr[i] = s[threadIdx.x] - v;
    if (threadIdx.x == 255) partial[blockIdx.x] = s[255];
}

__global__ void k_scan2(int* __restrict__ partial) {
    __shared__ int s[256];
    int v = (threadIdx.x < SCAN_NB) ? partial[threadIdx.x] : 0;
    s[threadIdx.x] = v;
    __syncthreads();
    for (int off = 1; off < 256; off <<= 1) {
        int t = (threadIdx.x >= off) ? s[threadIdx.x - off] : 0;
        __syncthreads();
        s[threadIdx.x] += t;
        __syncthreads();
    }
    if (threadIdx.x < SCAN_NB) partial[threadIdx.x] = s[threadIdx.x] - v;
}

__global__ void k_scan3(int* __restrict__ rowptr, const int* __restrict__ partial) {
    int i = blockIdx.x * 256 + threadIdx.x;
    if (i < N_NODES) rowptr[i] += partial[blockIdx.x];
    if (i == 0) rowptr[N_NODES] = E_TOT;
}

__global__ void k_fill_self(const int* __restrict__ rowptr, const float* __restrict__ dinv,
                            int* __restrict__ csr_src, float* __restrict__ csr_norm,
                            int* __restrict__ cursor) {
    int i = blockIdx.x * blockDim.x + threadIdx.x;
    if (i >= N_NODES) return;
    int p = rowptr[i];
    csr_src[p] = i;
    float di = dinv[i];
    csr_norm[p] = di * di;
    cursor[i] = 1;
}

__global__ void k_fill_edge(const int* __restrict__ srcp, const int* __restrict__ dstp,
                            const int* __restrict__ rowptr, const float* __restrict__ dinv,
                            int* __restrict__ cursor, int* __restrict__ csr_src,
                            float* __restrict__ csr_norm) {
    int e = blockIdx.x * blockDim.x + threadIdx.x;
    if (e >= N_EDGES) return;
    int s = srcp[e], d = dstp[e];
    int p = rowptr[d] + atomicAdd(&cursor[d], 1);
    csr_src[p] = s;
    csr_norm[p] = dinv[s] * dinv[d];
}

// ---------------- GEMM ----------------
template <int K>
__global__ void k_gemm64(const float* __restrict__ x, const float* __restrict__ w,
                         float* __restrict__ out, int ncol, int nrows) {
    __shared__ float sw[K * 64];
    int col_off = blockIdx.y * 64;
    for (int i = threadIdx.x; i < K * 64; i += 256) {
        int k = i >> 6, j = i & 63;
        sw[i] = w[k * ncol + col_off + j];
    }
    __syncthreads();
    int row0 = blockIdx.x * 64;
#pragma unroll
    for (int it = 0; it < 16; ++it) {
        int idx = it * 256 + threadIdx.x;
        int r = row0 + (idx >> 6);
        int j = idx & 63;
        if (r < nrows) {
            const float4* xr4 = (const float4*)(x + (size_t)r * K);
            float acc = 0.f;
#pragma unroll
            for (int k4 = 0; k4 < K / 4; ++k4) {
                float4 xv = xr4[k4];
                acc = fmaf(xv.x, sw[(4 * k4 + 0) * 64 + j], acc);
                acc = fmaf(xv.y, sw[(4 * k4 + 1) * 64 + j], acc);
                acc = fmaf(xv.z, sw[(4 * k4 + 2) * 64 + j], acc);
                acc = fmaf(xv.w, sw[(4 * k4 + 3) * 64 + j], acc);
            }
            out[(size_t)r * ncol + col_off + j] = acc;
        }
    }
}

// ---------------- GCN aggregate: wave/node, float4 lanes, 4 edges per pass ----------------
__global__ void k_gcn_gather4(const int* __restrict__ rowptr, const int* __restrict__ csr_src,
                              const float* __restrict__ csr_norm, const float* __restrict__ t,
                              const float* __restrict__ b, float* __restrict__ out) {
    int node = (blockIdx.x * blockDim.x + threadIdx.x) >> 6;
    int lane = threadIdx.x & 63;
    if (node >= N_NODES) return;
    int sub = lane >> 4, l16 = lane & 15;
    int beg = rowptr[node], end = rowptr[node + 1];
    const float4* __restrict__ t4 = (const float4*)t;
    float4 acc = {0.f, 0.f, 0.f, 0.f};
    for (int p0 = beg; p0 < end; p0 += 4) {
        int p = p0 + sub;
        if (p < end) {
            int s = csr_src[p];
            float nm = csr_norm[p];
            float4 v = t4[(size_t)s * 16 + l16];
            acc.x = fmaf(nm, v.x, acc.x);
            acc.y = fmaf(nm, v.y, acc.y);
            acc.z = fmaf(nm, v.z, acc.z);
            acc.w = fmaf(nm, v.w, acc.w);
        }
    }
#pragma unroll
    for (int m = 16; m <= 32; m <<= 1) {
        acc.x += __shfl_xor(acc.x, m);
        acc.y += __shfl_xor(acc.y, m);
        acc.z += __shfl_xor(acc.z, m);
        acc.w += __shfl_xor(acc.w, m);
    }
    if (lane < 16) {
        float4 bv = ((const float4*)b)[l16];
        float4 r;
        r.x = fmaxf(acc.x + bv.x, 0.f);
        r.y = fmaxf(acc.y + bv.y, 0.f);
        r.z = fmaxf(acc.z + bv.z, 0.f);
        r.w = fmaxf(acc.w + bv.w, 0.f);
        ((float4*)out)[(size_t)node * 16 + l16] = r;
    }
}

// ---------------- GAT ----------------
// wat[q*64 + cin] = sum_c gat_w[cin, h*64+c] * att[h][c],  q = h*2 + (0:src,1:dst)
__global__ void k_wat(const float* __restrict__ gat_w, const float* __restrict__ att_src,
                      const float* __restrict__ att_dst, float* __restrict__ wat) {
    int t = threadIdx.x;  // 512 threads
    int q = t >> 6, cin = t & 63;
    int h = q >> 1;
    const float* av = (q & 1) ? att_dst : att_src;
    float acc = 0.f;
#pragma unroll
    for (int c = 0; c < 64; ++c)
        acc = fmaf(gat_w[cin * 256 + h * 64 + c], av[h * 64 + c], acc);
    wat[t] = acc;
}

// asrc/adst = bufA @ wat^T : wave per node
__global__ void k_att2(const float* __restrict__ xin, const float* __restrict__ wat,
                       float* __restrict__ asrc, float* __restrict__ adst) {
    __shared__ float sw[512];
    for (int i = threadIdx.x; i < 512; i += 256) sw[i] = wat[i];
    __syncthreads();
    int node = (blockIdx.x * blockDim.x + threadIdx.x) >> 6;
    int lane = threadIdx.x & 63;
    if (node >= N_NODES) return;
    float val = xin[(size_t)node * 64 + lane];
#pragma unroll
    for (int q = 0; q < 8; ++q) {
        float p = val * sw[q * 64 + lane];
#pragma unroll
        for (int m = 1; m <= 32; m <<= 1) p += __shfl_xor(p, m);
        if (lane == q) {
            if (q & 1) adst[node * 4 + (q >> 1)] = p;
            else       asrc[node * 4 + (q >> 1)] = p;
        }
    }
}

static __device__ __forceinline__ float lrelu02(float v) {
    return v >= 0.f ? v : 0.2f * v;
}

// per (edge,head) unnormalized exp + per (node,head) denominator
__global__ void k_gat_alpha(const int* __restrict__ rowptr, const int* __restrict__ csr_src,
                            const float* __restrict__ asrc, const float* __restrict__ adst,
                            float* __restrict__ ebuf, float* __restrict__ denom) {
    int node = (blockIdx.x * blockDim.x + threadIdx.x) >> 6;
    int lane = threadIdx.x & 63;
    if (node >= N_NODES) return;
    int h = lane & 3, esub = lane >> 2;  // 16 edges x 4 heads per pass
    int beg = rowptr[node], end = rowptr[node + 1];
    float ad = adst[node * 4 + h];
    float m = -1e30f;
    for (int base = beg; base < end; base += 16) {
        int e = base + esub;
        if (e < end) {
            int s = csr_src[e];
            m = fmaxf(m, lrelu02(asrc[s * 4 + h] + ad));
        }
    }
#pragma unroll
    for (int mk = 4; mk <= 32; mk <<= 1) m = fmaxf(m, __shfl_xor(m, mk));
    float den = 0.f;
    for (int base = beg; base < end; base += 16) {
        int e = base + esub;
        if (e < end) {
            int s = csr_src[e];
            float ex = expf(lrelu02(asrc[s * 4 + h] + ad) - m);
            den += ex;
            ebuf[e * 4 + h] = ex;  // == base*4 + lane : coalesced
        }
    }
#pragma unroll
    for (int mk = 4; mk <= 32; mk <<= 1) den += __shfl_xor(den, mk);
    if (lane < 4) denom[node * 4 + lane] = den;
}

// streaming aggregation: lane l owns head l>>4, features 4*(l&15)..+3
__global__ void k_gat_agg(const int* __restrict__ rowptr, const int* __restrict__ csr_src,
                          const float* __restrict__ ebuf, const float* __restrict__ denom,
                          const float* __restrict__ hg, const float* __restrict__ gb,
                          float* __restrict__ out) {
    int node = (blockIdx.x * blockDim.x + threadIdx.x) >> 6;
    int lane = threadIdx.x & 63;
    if (node >= N_NODES) return;
    int h = lane >> 4, l16 = lane & 15;
    int beg = rowptr[node], end = rowptr[node + 1];
    const float4* __restrict__ hg4 = (const float4*)hg;
    float4 acc = {0.f, 0.f, 0.f, 0.f};
    for (int p = beg; p < end; ++p) {
        int s = csr_src[p];
        float a = ebuf[p * 4 + h];
        float4 v = hg4[(size_t)s * 64 + lane];  // cols 4*lane..+3 == h*64 + 4*l16..+3
        acc.x = fmaf(a, v.x, acc.x);
        acc.y = fmaf(a, v.y, acc.y);
        acc.z = fmaf(a, v.z, acc.z);
        acc.w = fmaf(a, v.w, acc.w);
    }
    float inv = 1.0f / denom[node * 4 + h];
    acc.x *= inv; acc.y *= inv; acc.z *= inv; acc.w *= inv;
#pragma unroll
    for (int m = 16; m <= 32; m <<= 1) {
        acc.x += __shfl_xor(acc.x, m);
        acc.y += __shfl_xor(acc.y, m);
        acc.z += __shfl_xor(acc.z, m);
        acc.w += __shfl_xor(acc.w, m);
    }
    if (lane < 16) {
        float4 bv = ((const float4*)gb)[l16];
        float4 r;
        r.x = fmaxf(0.25f * acc.x + bv.x, 0.f);
        r.y = fmaxf(0.25f * acc.y + bv.y, 0.f);
        r.z = fmaxf(0.25f * acc.z + bv.z, 0.f);
        r.w = fmaxf(0.25f * acc.w + bv.w, 0.f);
        ((float4*)out)[(size_t)node * 16 + l16] = r;
    }
}

// ---------------- pool (batch sorted: run-length accumulate, 32 nodes/wave) ----------------
__global__ void k_pool2(const int* __restrict__ batch, const float* __restrict__ h,
                        float* __restrict__ psum, float* __restrict__ pcnt) {
    int wave = (blockIdx.x * blockDim.x + threadIdx.x) >> 6;
    int lane = threadIdx.x & 63;
    int n0 = wave * 32;
    if (n0 >= N_NODES) return;
    int nend = min(n0 + 32, N_NODES);
    int cur = batch[n0];
    float acc = 0.f, cnt = 0.f;
    for (int n = n0; n < nend; ++n) {
        int g = batch[n];
        if (g != cur) {
            atomicAdd(&psum[cur * 64 + lane], acc);
            if (lane == 0) atomicAdd(&pcnt[cur], cnt);
            acc = 0.f; cnt = 0.f; cur = g;
        }
        acc += h[(size_t)n * 64 + lane];
        cnt += 1.f;
    }
    atomicAdd(&psum[cur * 64 + lane], acc);
    if (lane == 0) atomicAdd(&pcnt[cur], cnt);
}

__global__ void k_cls(const float* __restrict__ psum, const float* __restrict__ pcnt,
                      const float* __restrict__ cw1, const float* __restrict__ cb1,
                      const float* __restrict__ cw2, const float* __restrict__ cb2,
                      float* __restrict__ out) {
    int g = blockIdx.x;
    int j = threadIdx.x;
    __shared__ float sp[64];
    float rc = 1.0f / fmaxf(pcnt[g], 1.0f);
    sp[j] = psum[g * 64 + j] * rc;
    __syncthreads();
    float z = 0.f;
    if (j < 32) {
        float acc = 0.f;
#pragma unroll
        for (int k = 0; k < 64; ++k) acc = fmaf(sp[k], cw1[k * 32 + j], acc);
        acc += cb1[j];
        acc = fmaxf(acc, 0.f);
        z = acc * cw2[j];
    }
#pragma unroll
    for (int off = 32; off; off >>= 1) z += __shfl_down(z, off);
    if (j == 0) out[g] = z + cb2[0];
}

extern "C" void kernel_launch(void* const* d_in, const int* in_sizes, int n_in,
                              void* d_out, int out_size, void* d_ws, size_t ws_size,
                              hipStream_t stream) {
    const float* x       = (const float*)d_in[0];
    const int*   ei      = (const int*)d_in[1];
    const int*   batch   = (const int*)d_in[2];
    const float* w1      = (const float*)d_in[3];
    const float* b1      = (const float*)d_in[4];
    const float* w2      = (const float*)d_in[5];
    const float* b2      = (const float*)d_in[6];
    const float* w3      = (const float*)d_in[7];
    const float* b3      = (const float*)d_in[8];
    const float* gat_w   = (const float*)d_in[9];
    const float* att_src = (const float*)d_in[10];
    const float* att_dst = (const float*)d_in[11];
    const float* gat_b   = (const float*)d_in[12];
    const float* cw1     = (const float*)d_in[13];
    const float* cb1     = (const float*)d_in[14];
    const float* cw2     = (const float*)d_in[15];
    const float* cb2     = (const float*)d_in[16];
    float* out = (float*)d_out;

    const int* srcp = ei;
    const int* dstp = ei + N_EDGES;

    float* W = (float*)d_ws;
    size_t off = 0;
    float*    dinv    = W + off; off += N_NODES;
    int*      degi    = (int*)(W + off); off += N_NODES;
    int*      rowptr  = (int*)(W + off); off += N_NODES + 1;
    int*      partial = (int*)(W + off); off += 256;
    int*      cursor  = (int*)(W + off); off += N_NODES;
    int*      csr_src = (int*)(W + off); off += E_TOT;
    float*    csr_nrm = W + off; off += E_TOT;
    float*    bufT    = W + off; off += (size_t)N_NODES * HID;
    float*    bufA    = W + off; off += (size_t)N_NODES * HID;
    float*    bufB    = W + off; off += (size_t)N_NODES * HID;
    float*    hg      = W + off; off += (size_t)N_NODES * 256;
    float*    asrc    = W + off; off += (size_t)N_NODES * 4;
    float*    adst    = W + off; off += (size_t)N_NODES * 4;
    float*    ebuf    = W + off; off += (size_t)E_TOT * 4;
    float*    denom   = W + off; off += (size_t)N_NODES * 4;
    float*    wat     = W + off; off += 512;
    float*    psum    = W + off; off += (size_t)N_GRAPHS * HID;
    float*    pcnt    = W + off; off += N_GRAPHS;

    auto cdiv = [](int a, int b) { return (a + b - 1) / b; };

    hipMemsetAsync(degi, 0, N_NODES * sizeof(int), stream);
    hipMemsetAsync(psum, 0, (N_GRAPHS * HID + N_GRAPHS) * sizeof(float), stream);

    // degree / dinv / CSR
    k_deg<<<cdiv(N_EDGES, 256), 256, 0, stream>>>(dstp, degi);
    k_dinv<<<cdiv(N_NODES, 256), 256, 0, stream>>>(degi, dinv);
    k_scan1<<<SCAN_NB, 256, 0, stream>>>(degi, rowptr, partial);
    k_scan2<<<1, 256, 0, stream>>>(partial);
    k_scan3<<<SCAN_NB, 256, 0, stream>>>(rowptr, partial);
    k_fill_self<<<cdiv(N_NODES, 256), 256, 0, stream>>>(rowptr, dinv, csr_src, csr_nrm, cursor);
    k_fill_edge<<<cdiv(N_EDGES, 256), 256, 0, stream>>>(srcp, dstp, rowptr, dinv, cursor,
                                                        csr_src, csr_nrm);

    const int nWV = cdiv(N_NODES * 64, 256);  // wave-per-node kernels
    dim3 g64(cdiv(N_NODES, 64), 1);

    // GCN layer 1 (K=128): x -> bufA
    k_gemm64<F_IN><<<g64, 256, 0, stream>>>(x, w1, bufT, HID, N_NODES);
    k_gcn_gather4<<<nWV, 256, 0, stream>>>(rowptr, csr_src, csr_nrm, bufT, b1, bufA);

    // GCN layer 2: bufA -> bufB
    k_gemm64<HID><<<g64, 256, 0, stream>>>(bufA, w2, bufT, HID, N_NODES);
    k_gcn_gather4<<<nWV, 256, 0, stream>>>(rowptr, csr_src, csr_nrm, bufT, b2, bufB);

    // GCN layer 3: bufB -> bufA
    k_gemm64<HID><<<g64, 256, 0, stream>>>(bufB, w3, bufT, HID, N_NODES);
    k_gcn_gather4<<<nWV, 256, 0, stream>>>(rowptr, csr_src, csr_nrm, bufT, b3, bufA);

    // GAT
    dim3 gGAT(cdiv(N_NODES, 64), 4);
    k_gemm64<HID><<<gGAT, 256, 0, stream>>>(bufA, gat_w, hg, 4 * HID, N_NODES);
    k_wat<<<1, 512, 0, stream>>>(gat_w, att_src, att_dst, wat);
    k_att2<<<nWV, 256, 0, stream>>>(bufA, wat, asrc, adst);
    k_gat_alpha<<<nWV, 256, 0, stream>>>(rowptr, csr_src, asrc, adst, ebuf, denom);
    k_gat_agg<<<nWV, 256, 0, stream>>>(rowptr, csr_src, ebuf, denom, hg, gat_b, bufB);

    // pool + classifier
    k_pool2<<<cdiv(cdiv(N_NODES, 32) * 64, 256), 256, 0, stream>>>(batch, bufB, psum, pcnt);
    k_cls<<<N_GRAPHS, 64, 0, stream>>>(psum, pcnt, cw1, cb1, cw2, cb2, out);
}